// Round 1
// baseline (2141.477 us; speedup 1.0000x reference)
//
#include <hip/hip_runtime.h>

// Problem constants
#define CC   256          // input/output channels
#define CEE  64           // encoded channels
#define TT   16
#define KKK  7
#define PADK 3
#define GGG  4
#define CGP  16           // channels per group
#define K2G  196          // 49*4 corr channels
#define HHH  56
#define WWW  56
#define HW   3136
#define THW  50176        // T*H*W
#define BBB  4

// Workspace layout (in floats)
#define N_XENC   (BBB*CEE*THW)        // 12,845,056
#define OFF_XENC 0
#define OFF_EWT  (N_XENC)                    // enc_w transposed [c][o] : 256*64
#define OFF_ESC  (OFF_EWT + CC*CEE)          // 64
#define OFF_ESH  (OFF_ESC + CEE)             // 64
#define OFF_DWT  (OFF_ESH + CEE)             // dec_w transposed [f][o] : 196*256
#define OFF_DSC  (OFF_DWT + K2G*CC)          // 256
#define OFF_DSH  (OFF_DSC + CC)              // 256

// ---------------------------------------------------------------------------
// Prep: transpose weights, fold BN coefficients
// ---------------------------------------------------------------------------
__global__ void prep_kernel(const float* __restrict__ enc_w,
                            const float* __restrict__ eg, const float* __restrict__ eb,
                            const float* __restrict__ em, const float* __restrict__ ev,
                            const float* __restrict__ dec_w,
                            const float* __restrict__ dg, const float* __restrict__ db,
                            const float* __restrict__ dm, const float* __restrict__ dv,
                            float* __restrict__ ewt, float* __restrict__ esc, float* __restrict__ esh,
                            float* __restrict__ dwt, float* __restrict__ dsc, float* __restrict__ dsh) {
    int i = blockIdx.x * blockDim.x + threadIdx.x;
    int n = blockDim.x * gridDim.x;
    for (int idx = i; idx < CC * CEE; idx += n) {   // ewt[c*64+o] = enc_w[o*256+c]
        int c = idx >> 6, o = idx & 63;
        ewt[idx] = enc_w[o * CC + c];
    }
    for (int idx = i; idx < K2G * CC; idx += n) {   // dwt[f*256+o] = dec_w[o*196+f]
        int f = idx >> 8, o = idx & 255;
        dwt[idx] = dec_w[o * K2G + f];
    }
    for (int idx = i; idx < CEE; idx += n) {
        float inv = eg[idx] * rsqrtf(ev[idx] + 1e-5f);
        esc[idx] = inv;
        esh[idx] = eb[idx] - em[idx] * inv;
    }
    for (int idx = i; idx < CC; idx += n) {
        float inv = dg[idx] * rsqrtf(dv[idx] + 1e-5f);
        dsc[idx] = inv;
        dsh[idx] = db[idx] - dm[idx] * inv;
    }
}

// ---------------------------------------------------------------------------
// Enc: x_enc[b,o,q] = relu(scale[o]*(sum_c enc_w[o,c]*x[b,c,q]) + shift[o])
// Block: 256 threads, each owns one position q (256 consecutive q per block),
// 64 accumulators/thread. Weights staged in 64-c chunks in LDS [c][o].
// ---------------------------------------------------------------------------
__global__ void enc_kernel(const float* __restrict__ x, const float* __restrict__ ewt,
                           const float* __restrict__ esc, const float* __restrict__ esh,
                           float* __restrict__ xenc) {
    __shared__ float wlds[64 * 64];
    const int tid = threadIdx.x;
    const int b = blockIdx.x / 196;
    const int q = (blockIdx.x % 196) * 256 + tid;
    const float* xb = x + (size_t)b * CC * THW + q;

    float acc[64];
    #pragma unroll
    for (int i = 0; i < 64; ++i) acc[i] = 0.f;

    #pragma unroll 1
    for (int chunk = 0; chunk < 4; ++chunk) {
        __syncthreads();
        // stage 64x64 weight chunk: wlds[c_local*64+o]
        const float4* src = (const float4*)(ewt + chunk * 4096);
        float4* dst = (float4*)wlds;
        #pragma unroll
        for (int k = 0; k < 4; ++k) dst[k * 256 + tid] = src[k * 256 + tid];
        __syncthreads();

        #pragma unroll 1
        for (int sub = 0; sub < 4; ++sub) {
            float xv[16];
            #pragma unroll
            for (int j = 0; j < 16; ++j)
                xv[j] = xb[(chunk * 64 + sub * 16 + j) * THW];
            #pragma unroll
            for (int j = 0; j < 16; ++j) {
                const float4* wr = ((const float4*)wlds) + (sub * 16 + j) * 16;
                #pragma unroll
                for (int oi = 0; oi < 16; ++oi) {
                    float4 w4 = wr[oi];
                    acc[4 * oi + 0] += w4.x * xv[j];
                    acc[4 * oi + 1] += w4.y * xv[j];
                    acc[4 * oi + 2] += w4.z * xv[j];
                    acc[4 * oi + 3] += w4.w * xv[j];
                }
            }
        }
    }

    const int outbase = b * CEE * THW + q;
    #pragma unroll
    for (int o = 0; o < 64; ++o) {
        float v = acc[o] * esc[o] + esh[o];
        xenc[outbase + o * THW] = v > 0.f ? v : 0.f;
    }
}

// ---------------------------------------------------------------------------
// Fused correlation + dec conv + BN + residual relu.
// Block: 256 threads = 4 waves (wave index g), 8x8 spatial tile, fixed (b,t).
// Stage 1 (per ky): corr[kx*4+g][p] for the 8x8 tile, from LDS x2 tile +
//   register x1 + LDS wgt. Stage 2: accumulate dec GEMM chunk (28 f) into
//   64 regs/thread (o = g*64..g*64+63, p = lane).
// ---------------------------------------------------------------------------
__global__ void corr_dec_kernel(const float* __restrict__ x, const float* __restrict__ xenc,
                                const float* __restrict__ fw, const float* __restrict__ dwt,
                                const float* __restrict__ dsc, const float* __restrict__ dsh,
                                float* __restrict__ out) {
    __shared__ float x2t[64 * 196];   // [c][hy*14+hx]
    __shared__ float wg[64 * 49];     // [c][ky*7+kx], pre-scaled by 1/16
    __shared__ float corr[28 * 64];   // [kx*4+g][p]

    const int tid = threadIdx.x;
    const int g = tid >> 6;
    const int lane = tid & 63;
    const int ph = lane >> 3;
    const int pw = lane & 7;

    const int bx = blockIdx.x;
    const int tile = bx % 49;
    const int t = (bx / 49) & 15;
    const int b = bx / 784;
    const int th0 = (tile / 7) * 8;
    const int tw0 = (tile % 7) * 8;

    // ---- load x2 tile (14x14 halo, zero-padded) ----
    for (int i = tid; i < 64 * 196; i += 256) {
        int c = i / 196;
        int hw = i - c * 196;
        int hy = hw / 14;
        int hx = hw - hy * 14;
        int h = th0 + hy - PADK;
        int w = tw0 + hx - PADK;
        float v = 0.f;
        if ((unsigned)h < HHH && (unsigned)w < WWW)
            v = xenc[((b * CEE + c) * TT + t) * HW + h * WWW + w];
        x2t[i] = v;
    }
    // ---- load wgt for this t, scaled by 1/16 ----
    for (int i = tid; i < 64 * 49; i += 256) {
        int c = i / 49;
        int o = i - c * 49;
        wg[i] = fw[c * (TT * 49) + t * 49 + o] * (1.f / 16.f);
    }
    // ---- load x1 (time-shifted) into registers ----
    const int tprev = t > 0 ? t - 1 : 0;
    const int hwp = (th0 + ph) * WWW + (tw0 + pw);
    float x1r[16];
    #pragma unroll
    for (int j = 0; j < 16; ++j)
        x1r[j] = xenc[((b * CEE + g * CGP + j) * TT + tprev) * HW + hwp];

    float acc2[64];
    #pragma unroll
    for (int i = 0; i < 64; ++i) acc2[i] = 0.f;

    __syncthreads();

    #pragma unroll 1
    for (int ky = 0; ky < 7; ++ky) {
        // ---- stage 1: correlation for this ky ----
        float a[7];
        #pragma unroll
        for (int kx = 0; kx < 7; ++kx) a[kx] = 0.f;
        #pragma unroll
        for (int j = 0; j < 16; ++j) {
            const float x1v = x1r[j];
            const int crow = g * CGP + j;
            const float* x2row = &x2t[crow * 196 + (ph + ky) * 14 + pw];
            const float* wrow = &wg[crow * 49 + ky * 7];
            #pragma unroll
            for (int kx = 0; kx < 7; ++kx)
                a[kx] += wrow[kx] * (x1v * x2row[kx]);
        }
        #pragma unroll
        for (int kx = 0; kx < 7; ++kx)
            corr[(kx * 4 + g) * 64 + lane] = a[kx];
        __syncthreads();

        // ---- stage 2: dec GEMM over this ky's 28 corr channels ----
        #pragma unroll
        for (int fl = 0; fl < 28; ++fl) {
            const int kx = fl >> 2;
            const int gg = fl & 3;
            const int f = (ky * 7 + kx) * 4 + gg;
            const float cv = corr[fl * 64 + lane];
            const float4* wr = (const float4*)(dwt + f * CC + g * 64);
            #pragma unroll
            for (int oi = 0; oi < 16; ++oi) {
                float4 w4 = wr[oi];
                acc2[4 * oi + 0] += w4.x * cv;
                acc2[4 * oi + 1] += w4.y * cv;
                acc2[4 * oi + 2] += w4.z * cv;
                acc2[4 * oi + 3] += w4.w * cv;
            }
        }
        __syncthreads();
    }

    // ---- epilogue: BN + residual relu ----
    #pragma unroll
    for (int i = 0; i < 64; ++i) {
        const int o = g * 64 + i;
        const int idx = ((b * CC + o) * TT + t) * HW + hwp;
        float v = acc2[i] * dsc[o] + dsh[o];
        float r = x[idx] + v;
        out[idx] = r > 0.f ? r : 0.f;
    }
}

// ---------------------------------------------------------------------------
extern "C" void kernel_launch(void* const* d_in, const int* in_sizes, int n_in,
                              void* d_out, int out_size, void* d_ws, size_t ws_size,
                              hipStream_t stream) {
    const float* x     = (const float*)d_in[0];
    const float* enc_w = (const float*)d_in[1];
    const float* eg    = (const float*)d_in[2];
    const float* eb    = (const float*)d_in[3];
    const float* em    = (const float*)d_in[4];
    const float* ev    = (const float*)d_in[5];
    const float* fw    = (const float*)d_in[6];
    const float* dec_w = (const float*)d_in[7];
    const float* dg    = (const float*)d_in[8];
    const float* db    = (const float*)d_in[9];
    const float* dm    = (const float*)d_in[10];
    const float* dv    = (const float*)d_in[11];
    float* out = (float*)d_out;
    float* ws  = (float*)d_ws;

    prep_kernel<<<104, 256, 0, stream>>>(enc_w, eg, eb, em, ev, dec_w, dg, db, dm, dv,
                                         ws + OFF_EWT, ws + OFF_ESC, ws + OFF_ESH,
                                         ws + OFF_DWT, ws + OFF_DSC, ws + OFF_DSH);
    enc_kernel<<<784, 256, 0, stream>>>(x, ws + OFF_EWT, ws + OFF_ESC, ws + OFF_ESH,
                                        ws + OFF_XENC);
    corr_dec_kernel<<<3136, 256, 0, stream>>>(x, ws + OFF_XENC, fw,
                                              ws + OFF_DWT, ws + OFF_DSC, ws + OFF_DSH,
                                              out);
}

// Round 2
// 881.440 us; speedup vs baseline: 2.4295x; 2.4295x over previous
//
#include <hip/hip_runtime.h>

// Problem constants
#define CC   256          // input/output channels
#define CEE  64           // encoded channels
#define TT   16
#define KKK  7
#define PADK 3
#define GGG  4
#define CGP  16           // channels per group
#define K2G  196          // 49*4 corr channels
#define KPAD 224          // 7 ky * 32 padded k-slots
#define HHH  56
#define WWW  56
#define HW   3136
#define THW  50176        // T*H*W
#define BBB  4

typedef _Float16 f16x8 __attribute__((ext_vector_type(8)));
typedef float    f32x4 __attribute__((ext_vector_type(4)));

// Workspace layout (in floats/dwords)
#define N_XENC   (BBB*CEE*THW)               // 12,845,056
#define OFF_XENC 0
#define OFF_EWT  (N_XENC)                    // enc_w transposed [c][o] : 256*64 fp32
#define OFF_ESC  (OFF_EWT + CC*CEE)          // 64
#define OFF_ESH  (OFF_ESC + CEE)             // 64
#define OFF_DWTH (OFF_ESH + CEE)             // dec_w fp16 [o=256][k=224] : 28672 dwords
#define OFF_DSC  (OFF_DWTH + (CC*KPAD)/2)    // 256
#define OFF_DSH  (OFF_DSC + CC)              // 256

// ---------------------------------------------------------------------------
// Prep: transpose enc weights, build fp16 dec weights in MFMA-K order,
// fold BN coefficients.
// K-slot order: k = ky*32 + g*8 + kx  (kx==7 -> zero pad), f = (ky*7+kx)*4+g
// ---------------------------------------------------------------------------
__global__ void prep_kernel(const float* __restrict__ enc_w,
                            const float* __restrict__ eg, const float* __restrict__ eb,
                            const float* __restrict__ em, const float* __restrict__ ev,
                            const float* __restrict__ dec_w,
                            const float* __restrict__ dg, const float* __restrict__ db,
                            const float* __restrict__ dm, const float* __restrict__ dv,
                            float* __restrict__ ewt, float* __restrict__ esc, float* __restrict__ esh,
                            _Float16* __restrict__ dwth, float* __restrict__ dsc, float* __restrict__ dsh) {
    int i = blockIdx.x * blockDim.x + threadIdx.x;
    int n = blockDim.x * gridDim.x;
    for (int idx = i; idx < CC * CEE; idx += n) {   // ewt[c*64+o] = enc_w[o*256+c]
        int c = idx >> 6, o = idx & 63;
        ewt[idx] = enc_w[o * CC + c];
    }
    for (int idx = i; idx < CC * KPAD; idx += n) {  // dwth[o*224+k]
        int o = idx / KPAD;
        int k = idx - o * KPAD;
        int ky = k >> 5, rem = k & 31, gg = rem >> 3, kx = rem & 7;
        float v = 0.f;
        if (kx < 7) v = dec_w[o * K2G + (ky * 7 + kx) * GGG + gg];
        dwth[idx] = (_Float16)v;
    }
    for (int idx = i; idx < CEE; idx += n) {
        float inv = eg[idx] * rsqrtf(ev[idx] + 1e-5f);
        esc[idx] = inv;
        esh[idx] = eb[idx] - em[idx] * inv;
    }
    for (int idx = i; idx < CC; idx += n) {
        float inv = dg[idx] * rsqrtf(dv[idx] + 1e-5f);
        dsc[idx] = inv;
        dsh[idx] = db[idx] - dm[idx] * inv;
    }
}

// ---------------------------------------------------------------------------
// Enc: x_enc[b,o,q] = relu(scale[o]*(sum_c enc_w[o,c]*x[b,c,q]) + shift[o])
// Same structure as R1 but with software-pipelined x loads (double-buffered
// xv) so the 16 stride-THW loads of sub-chunk s+1 overlap the 1024-FMA burst
// of sub-chunk s.
// ---------------------------------------------------------------------------
__global__ void __launch_bounds__(256) enc_kernel(
        const float* __restrict__ x, const float* __restrict__ ewt,
        const float* __restrict__ esc, const float* __restrict__ esh,
        float* __restrict__ xenc) {
    __shared__ float wlds[64 * 64];
    const int tid = threadIdx.x;
    const int b = blockIdx.x / 196;
    const int q = (blockIdx.x % 196) * 256 + tid;
    const float* xb = x + (size_t)b * CC * THW + q;

    float acc[64];
    #pragma unroll
    for (int i = 0; i < 64; ++i) acc[i] = 0.f;

    #pragma unroll 1
    for (int chunk = 0; chunk < 4; ++chunk) {
        __syncthreads();
        const float4* src = (const float4*)(ewt + chunk * 4096);
        float4* dst = (float4*)wlds;
        #pragma unroll
        for (int k = 0; k < 4; ++k) dst[k * 256 + tid] = src[k * 256 + tid];
        __syncthreads();

        float xv[16];
        #pragma unroll
        for (int j = 0; j < 16; ++j)
            xv[j] = xb[(chunk * 64 + j) * THW];

        #pragma unroll 1
        for (int sub = 0; sub < 4; ++sub) {
            float xvn[16];
            if (sub < 3) {
                #pragma unroll
                for (int j = 0; j < 16; ++j)
                    xvn[j] = xb[(chunk * 64 + (sub + 1) * 16 + j) * THW];
            }
            #pragma unroll
            for (int j = 0; j < 16; ++j) {
                const float4* wr = ((const float4*)wlds) + (sub * 16 + j) * 16;
                #pragma unroll
                for (int oi = 0; oi < 16; ++oi) {
                    float4 w4 = wr[oi];
                    acc[4 * oi + 0] += w4.x * xv[j];
                    acc[4 * oi + 1] += w4.y * xv[j];
                    acc[4 * oi + 2] += w4.z * xv[j];
                    acc[4 * oi + 3] += w4.w * xv[j];
                }
            }
            if (sub < 3) {
                #pragma unroll
                for (int j = 0; j < 16; ++j) xv[j] = xvn[j];
            }
        }
    }

    const int outbase = b * CEE * THW + q;
    #pragma unroll
    for (int o = 0; o < 64; ++o) {
        float v = acc[o] * esc[o] + esh[o];
        xenc[outbase + o * THW] = v > 0.f ? v : 0.f;
    }
}

// ---------------------------------------------------------------------------
// Fused correlation + dec MFMA GEMM + BN + residual relu.
// Block: 256 threads = 4 waves, 8x8 spatial tile, fixed (b,t).
// Stage 1 (per ky, fp32 VALU): wave g computes corr for its channel group,
//   7 kx values per thread, packed fp16 into corr_h[p=lane][k=g*8+kx].
// Stage 2 (per ky, MFMA fp16): D[o][p] += dwt_h[o][k] * corr_h[k][p] via
//   mfma_f32_16x16x32_f16. Wave w owns o in [w*64, w*64+64).
//   A-frag (dwt): lane holds A[m=lane&15][k=quad*8+j] -> 16B global load.
//   B-frag (corr): lane holds B[k=quad*8+j][n=lane&15] -> 16B LDS load.
//   D: row(o)=quad*4+reg, col(p)=lane&15 -> 32B-coalesced stores.
// ---------------------------------------------------------------------------
__global__ void __launch_bounds__(256) corr_dec_kernel(
        const float* __restrict__ x, const float* __restrict__ xenc,
        const float* __restrict__ fw, const _Float16* __restrict__ dwth,
        const float* __restrict__ dsc, const float* __restrict__ dsh,
        float* __restrict__ out) {
    __shared__ float x2t[64 * 196];                 // [c][hy*14+hx]  (50176 B)
    __shared__ float wg[64 * 49];                   // [c][ky*7+kx] / 16  (12544 B)
    __shared__ __align__(16) _Float16 corr_h[64 * 32]; // [p][k-slot]  (4096 B)

    const int tid = threadIdx.x;
    const int g = tid >> 6;        // wave id: stage1 channel group, stage2 o-block
    const int lane = tid & 63;
    const int ph = lane >> 3;
    const int pw = lane & 7;

    const int bx = blockIdx.x;
    const int tile = bx % 49;
    const int t = (bx / 49) & 15;
    const int b = bx / 784;
    const int th0 = (tile / 7) * 8;
    const int tw0 = (tile % 7) * 8;

    // ---- load x2 tile (14x14 halo, zero-padded) ----
    for (int i = tid; i < 64 * 196; i += 256) {
        int c = i / 196;
        int hw = i - c * 196;
        int hy = hw / 14;
        int hx = hw - hy * 14;
        int h = th0 + hy - PADK;
        int w = tw0 + hx - PADK;
        float v = 0.f;
        if ((unsigned)h < HHH && (unsigned)w < WWW)
            v = xenc[((b * CEE + c) * TT + t) * HW + h * WWW + w];
        x2t[i] = v;
    }
    // ---- load wgt for this t, scaled by 1/16 ----
    for (int i = tid; i < 64 * 49; i += 256) {
        int c = i / 49;
        int o = i - c * 49;
        wg[i] = fw[c * (TT * 49) + t * 49 + o] * (1.f / 16.f);
    }
    // ---- load x1 (time-shifted) into registers ----
    const int tprev = t > 0 ? t - 1 : 0;
    const int hwp = (th0 + ph) * WWW + (tw0 + pw);
    float x1r[16];
    #pragma unroll
    for (int j = 0; j < 16; ++j)
        x1r[j] = xenc[((b * CEE + g * CGP + j) * TT + tprev) * HW + hwp];

    f32x4 acc[4][4];
    #pragma unroll
    for (int mi = 0; mi < 4; ++mi)
        #pragma unroll
        for (int ni = 0; ni < 4; ++ni)
            acc[mi][ni] = (f32x4){0.f, 0.f, 0.f, 0.f};

    const int r16 = lane & 15;
    const int quad = lane >> 4;

    __syncthreads();

    #pragma unroll 1
    for (int ky = 0; ky < 7; ++ky) {
        // ---- stage 1: correlation for this ky (fp32) ----
        float a[7];
        #pragma unroll
        for (int kx = 0; kx < 7; ++kx) a[kx] = 0.f;
        #pragma unroll
        for (int j = 0; j < 16; ++j) {
            const float x1v = x1r[j];
            const int crow = g * CGP + j;
            const float* x2row = &x2t[crow * 196 + (ph + ky) * 14 + pw];
            const float* wrow = &wg[crow * 49 + ky * 7];
            #pragma unroll
            for (int kx = 0; kx < 7; ++kx)
                a[kx] += wrow[kx] * (x1v * x2row[kx]);
        }
        f16x8 pk;
        #pragma unroll
        for (int kx = 0; kx < 7; ++kx) pk[kx] = (_Float16)a[kx];
        pk[7] = (_Float16)0.f;
        *(f16x8*)(corr_h + lane * 32 + g * 8) = pk;

        // ---- prefetch A-frags (dwt, global, independent of corr_h) ----
        f16x8 af[4];
        #pragma unroll
        for (int mi = 0; mi < 4; ++mi)
            af[mi] = *(const f16x8*)(dwth + (size_t)(g * 64 + mi * 16 + r16) * KPAD
                                     + ky * 32 + quad * 8);

        __syncthreads();

        // ---- stage 2: MFMA over this ky's 32 k-slots ----
        f16x8 bf[4];
        #pragma unroll
        for (int ni = 0; ni < 4; ++ni)
            bf[ni] = *(const f16x8*)(corr_h + (ni * 16 + r16) * 32 + quad * 8);
        #pragma unroll
        for (int mi = 0; mi < 4; ++mi)
            #pragma unroll
            for (int ni = 0; ni < 4; ++ni)
                acc[mi][ni] = __builtin_amdgcn_mfma_f32_16x16x32_f16(af[mi], bf[ni],
                                                                     acc[mi][ni], 0, 0, 0);
        __syncthreads();
    }

    // ---- epilogue: BN + residual relu ----
    #pragma unroll
    for (int mi = 0; mi < 4; ++mi) {
        #pragma unroll
        for (int reg = 0; reg < 4; ++reg) {
            const int o = g * 64 + mi * 16 + quad * 4 + reg;
            const float sc = dsc[o];
            const float sh = dsh[o];
            const int obase = ((b * CC + o) * TT + t) * HW;
            #pragma unroll
            for (int ni = 0; ni < 4; ++ni) {
                const int p = ni * 16 + r16;
                const int idx = obase + (th0 + (p >> 3)) * WWW + tw0 + (p & 7);
                float v = acc[mi][ni][reg] * sc + sh;
                float rr = x[idx] + v;
                out[idx] = rr > 0.f ? rr : 0.f;
            }
        }
    }
}

// ---------------------------------------------------------------------------
extern "C" void kernel_launch(void* const* d_in, const int* in_sizes, int n_in,
                              void* d_out, int out_size, void* d_ws, size_t ws_size,
                              hipStream_t stream) {
    const float* x     = (const float*)d_in[0];
    const float* enc_w = (const float*)d_in[1];
    const float* eg    = (const float*)d_in[2];
    const float* eb    = (const float*)d_in[3];
    const float* em    = (const float*)d_in[4];
    const float* ev    = (const float*)d_in[5];
    const float* fw    = (const float*)d_in[6];
    const float* dec_w = (const float*)d_in[7];
    const float* dg    = (const float*)d_in[8];
    const float* db    = (const float*)d_in[9];
    const float* dm    = (const float*)d_in[10];
    const float* dv    = (const float*)d_in[11];
    float* out = (float*)d_out;
    float* ws  = (float*)d_ws;

    prep_kernel<<<104, 256, 0, stream>>>(enc_w, eg, eb, em, ev, dec_w, dg, db, dm, dv,
                                         ws + OFF_EWT, ws + OFF_ESC, ws + OFF_ESH,
                                         (_Float16*)(ws + OFF_DWTH),
                                         ws + OFF_DSC, ws + OFF_DSH);
    enc_kernel<<<784, 256, 0, stream>>>(x, ws + OFF_EWT, ws + OFF_ESC, ws + OFF_ESH,
                                        ws + OFF_XENC);
    corr_dec_kernel<<<3136, 256, 0, stream>>>(x, ws + OFF_XENC, fw,
                                              (const _Float16*)(ws + OFF_DWTH),
                                              ws + OFF_DSC, ws + OFF_DSH,
                                              out);
}